// Round 8
// baseline (10805.864 us; speedup 1.0000x reference)
//
#include <hip/hip_runtime.h>

// ---------------------------------------------------------------------------
// 2-layer GRU (H=256, B=512, T=1024, I=1) + FC on MI355X.
//
// ROUND-8 RESTRUCTURE: weights live in LDS, not registers.
// Rounds 2-7 proved the compiler will not keep a 192-dword weight array in
// VGPRs (VGPR_Count=128 under 4 different knobs; per-step L2 re-reads ~300us
// per F dispatch). New structure:
//   - 16 groups x 32 batch rows. Per group:
//       L0: 4 blocks, each owns 64 h-cols; w_hh0 slice [192 cols][256] f16
//           = 96KB in LDS.
//       L1: 8 blocks, each owns 32 h-cols; w_hh1 + w_ih1 slices (48+48KB)
//           in LDS. gx1 = w_ih1 @ h0(t) is fused here as MFMAs (the old
//           gemm kernel + h0c/gxc staging are GONE).
//   - Single persistent dispatch, 192 blocks <= 256 CUs, 1 block/CU forced
//     by LDS -> co-residency guaranteed. Lag-1 layer pipeline.
//   - h exchanged via global (L2/L3) with relaxed agent-scope dword atomics;
//     monotonic arrival flags (f0: L0 arrivals, f1: L1 arrivals, c0: L1
//     consumption acks guarding the h0 ring-4 overwrite).
//   - Per-step floor: LDS weight stream 96KB -> ~768 clk; MFMA 48/wave.
// ---------------------------------------------------------------------------

#define HH 256
#define TT 1024
#define BB 512
#define NG 16                 // groups of 32 batch rows

typedef float        f32x4 __attribute__((ext_vector_type(4)));
typedef int          i32x4 __attribute__((ext_vector_type(4)));
typedef _Float16     f16x8 __attribute__((ext_vector_type(8)));
typedef unsigned int uint;

__device__ __forceinline__ float fsigm(float v) {
    return __builtin_amdgcn_rcpf(1.f + __expf(-v));
}
__device__ __forceinline__ float ftanh(float v) {
    return 1.f - 2.f * __builtin_amdgcn_rcpf(__expf(2.f * v) + 1.f);
}
__device__ __forceinline__ void spin_ge(uint* p, uint tgt) {
    while (__hip_atomic_load(p, __ATOMIC_ACQUIRE, __HIP_MEMORY_SCOPE_AGENT) < tgt)
        __builtin_amdgcn_s_sleep(1);
}
__device__ __forceinline__ uint ld_rel(const uint* p) {
    return __hip_atomic_load(p, __ATOMIC_RELAXED, __HIP_MEMORY_SCOPE_AGENT);
}
__device__ __forceinline__ void st_rel(uint* p, uint v) {
    __hip_atomic_store(p, v, __ATOMIC_RELAXED, __HIP_MEMORY_SCOPE_AGENT);
}

// h buffers: [kb=col>>3][row][8 f16] per slot; slot = 4096 u32 = 16KB.
// A-frag for mfma: lane(cl,kg), m-tile mt, k-chunk kk reads 16B at
// (kb=(kk*4+kg))*32 + (mt*16+cl), giving h[row=mt*16+cl][k=kb*8..+8].

// ---------------------------------------------------------------------------
// L0 block: group g, member m in [0,4). Owns h-cols [m*64, m*64+64).
// 4 waves; wave w owns cols m*64 + 16w + cl for gates r,z,n
// (weight n-tiles {w, 4+w, 8+w}).
// ---------------------------------------------------------------------------
__device__ __forceinline__ void
rec0_body(int g, int m, _Float16* Wlds,
          const _Float16* __restrict__ wl0, const float* __restrict__ x,
          const float* __restrict__ bih0, const float* __restrict__ bhh0,
          const float* __restrict__ wih0,
          uint* hbuf0, uint* flags)
{
    const int tid = threadIdx.x;
    const int w = tid >> 6, l = tid & 63, cl = l & 15, kg = l >> 4;

    // stage weight slice (96KB) into LDS once
    for (int i = 0; i < 24; ++i) {
        int u = i * 256 + tid;                       // 0..6143 units of 16B
        *(f32x4*)&Wlds[u * 8] = *(const f32x4*)(wl0 + ((size_t)m * 6144 + u) * 8);
    }

    const int c = m * 64 + w * 16 + cl;              // owned h-col
    const float b_r = bhh0[c] + bih0[c];
    const float b_z = bhh0[HH + c] + bih0[HH + c];
    const float b_nh = bhh0[2 * HH + c];
    const float b_ni = bih0[2 * HH + c];
    const float wir = wih0[c], wiz = wih0[HH + c], win = wih0[2 * HH + c];

    float hm[8];
#pragma unroll
    for (int j = 0; j < 8; ++j) hm[j] = 0.f;

    uint* f0 = flags + g * 16;
    uint* c0 = flags + 256 + g * 16;
    uint* hb_base = hbuf0 + (size_t)g * 4 * 4096;
    __syncthreads();

    for (int t = 0; t < TT; ++t) {
        if (tid == 0) {
            spin_ge(f0, 4u * t);                     // siblings wrote h(t-1)
            if (t >= 4) spin_ge(c0, 8u * (t - 3));   // L1 consumed h0(t-4)
        }
        __syncthreads();

        // x inputs for owned rows
        float xv[8];
#pragma unroll
        for (int j8 = 0; j8 < 8; ++j8) {
            int row = (j8 >> 2) * 16 + kg * 4 + (j8 & 3);
            xv[j8] = x[(size_t)(g * 32 + row) * TT + t];
        }

        // A-frags of h(t-1) from slot (t-1)&3
        uint* hbr = hb_base + ((t + 3) & 3) * 4096;
        i32x4 av[2][8];
#pragma unroll
        for (int mt = 0; mt < 2; ++mt)
#pragma unroll
            for (int kk = 0; kk < 8; ++kk) {
                int idx = (((kk * 4 + kg) * 32) + mt * 16 + cl) * 4;
                i32x4 v;
#pragma unroll
                for (int d = 0; d < 4; ++d) v[d] = (int)ld_rel(hbr + idx + d);
                av[mt][kk] = v;
            }

        // MFMA: 3 gates x 8 k-chunks x 2 m-tiles
        f32x4 acc[2][3];
#pragma unroll
        for (int mt = 0; mt < 2; ++mt)
#pragma unroll
            for (int j = 0; j < 4; ++j) {
                acc[mt][0][j] = b_r; acc[mt][1][j] = b_z; acc[mt][2][j] = b_nh;
            }
#pragma unroll
        for (int gi = 0; gi < 3; ++gi)
#pragma unroll
            for (int kk = 0; kk < 8; ++kk) {
                f16x8 B = *(const f16x8*)&Wlds[(((((gi * 4 + w) * 8) + kk) * 4 + kg) * 16 + cl) * 8];
#pragma unroll
                for (int mt = 0; mt < 2; ++mt)
                    acc[mt][gi] = __builtin_amdgcn_mfma_f32_16x16x32_f16(
                        __builtin_bit_cast(f16x8, av[mt][kk]), B, acc[mt][gi], 0, 0, 0);
            }

        // activations + publish h(t) to slot t&3
        uint* hbw = hb_base + (t & 3) * 4096;
#pragma unroll
        for (int mt = 0; mt < 2; ++mt)
#pragma unroll
            for (int j = 0; j < 4; ++j) {
                int j8 = mt * 4 + j;
                int row = mt * 16 + kg * 4 + j;
                float r  = fsigm(acc[mt][0][j] + xv[j8] * wir);
                float z  = fsigm(acc[mt][1][j] + xv[j8] * wiz);
                float nn = ftanh(xv[j8] * win + b_ni + r * acc[mt][2][j]);
                float h  = nn + z * (hm[j8] - nn);
                hm[j8] = h;
                unsigned short hb16 = __builtin_bit_cast(unsigned short, (_Float16)h);
                int other = __shfl_xor((int)hb16, 1);
                if ((cl & 1) == 0) {
                    uint word = (uint)hb16 | ((uint)(unsigned short)other << 16);
                    st_rel(hbw + ((c >> 3) * 32 + row) * 4 + ((c & 7) >> 1), word);
                }
            }
        __syncthreads();                             // drains stores (waitcnt before barrier)
        if (tid == 0)
            __hip_atomic_fetch_add(f0, 1u, __ATOMIC_RELEASE, __HIP_MEMORY_SCOPE_AGENT);
    }
}

// ---------------------------------------------------------------------------
// L1 block: group g, member m in [0,8). Owns h-cols [m*32, m*32+32).
// Waves 0,1 compute (wave w: cols m*32+16w+cl, n-tiles {w,2+w,4+w});
// waves 2,3 only hit barriers. LDS: w_hh1 slice (48KB) + w_ih1 slice (48KB).
// ---------------------------------------------------------------------------
__device__ __forceinline__ void
rec1_body(int g, int m, _Float16* Wlds,
          const _Float16* __restrict__ wl1h, const _Float16* __restrict__ wl1i,
          const float* __restrict__ bih1, const float* __restrict__ bhh1,
          uint* hbuf0, uint* hbuf1, uint* flags, float* __restrict__ h1st)
{
    const int tid = threadIdx.x;
    const int w = tid >> 6, l = tid & 63, cl = l & 15, kg = l >> 4;

    for (int i = 0; i < 24; ++i) {
        int u = i * 256 + tid;                       // 0..6143
        const _Float16* src = (u < 3072)
            ? (wl1h + ((size_t)m * 3072 + u) * 8)
            : (wl1i + ((size_t)m * 3072 + (u - 3072)) * 8);
        *(f32x4*)&Wlds[u * 8] = *(const f32x4*)src;
    }

    const bool act = (w < 2);
    int c = 0;
    float b_r = 0, b_z = 0, b_nh = 0, b_ni = 0;
    if (act) {
        c = m * 32 + w * 16 + cl;
        b_r = bhh1[c] + bih1[c];
        b_z = bhh1[HH + c] + bih1[HH + c];
        b_nh = bhh1[2 * HH + c];
        b_ni = bih1[2 * HH + c];
    }
    float hm[8];
#pragma unroll
    for (int j = 0; j < 8; ++j) hm[j] = 0.f;

    uint* f0 = flags + g * 16;
    uint* c0 = flags + 256 + g * 16;
    uint* f1 = flags + 512 + g * 16;
    uint* hb0 = hbuf0 + (size_t)g * 4 * 4096;
    uint* hb1 = hbuf1 + (size_t)g * 2 * 4096;
    __syncthreads();

    for (int t = 0; t < TT; ++t) {
        if (tid == 0) {
            spin_ge(f0, 4u * (t + 1));               // h0(t) ready
            spin_ge(f1, 8u * t);                     // peers wrote h1(t-1)
        }
        __syncthreads();

        if (act) {
            // acc: 0=r(sum), 1=z(sum), 2=n_ih, 3=n_hh
            f32x4 acc[2][4];
#pragma unroll
            for (int mt = 0; mt < 2; ++mt)
#pragma unroll
                for (int j = 0; j < 4; ++j) {
                    acc[mt][0][j] = b_r;  acc[mt][1][j] = b_z;
                    acc[mt][2][j] = b_ni; acc[mt][3][j] = b_nh;
                }

            // --- phase ih: A = h0(t), B = w_ih1 slice (LDS offset 24576) ---
            {
                uint* hr = hb0 + (t & 3) * 4096;
                i32x4 av[2][8];
#pragma unroll
                for (int mt = 0; mt < 2; ++mt)
#pragma unroll
                    for (int kk = 0; kk < 8; ++kk) {
                        int idx = (((kk * 4 + kg) * 32) + mt * 16 + cl) * 4;
                        i32x4 v;
#pragma unroll
                        for (int d = 0; d < 4; ++d) v[d] = (int)ld_rel(hr + idx + d);
                        av[mt][kk] = v;
                    }
#pragma unroll
                for (int gi = 0; gi < 3; ++gi)
#pragma unroll
                    for (int kk = 0; kk < 8; ++kk) {
                        f16x8 B = *(const f16x8*)&Wlds[24576 + (((((gi * 2 + w) * 8) + kk) * 4 + kg) * 16 + cl) * 8];
                        const int ai = (gi == 2) ? 2 : gi;
#pragma unroll
                        for (int mt = 0; mt < 2; ++mt)
                            acc[mt][ai] = __builtin_amdgcn_mfma_f32_16x16x32_f16(
                                __builtin_bit_cast(f16x8, av[mt][kk]), B, acc[mt][ai], 0, 0, 0);
                    }
            }
            // --- phase hh: A = h1(t-1), B = w_hh1 slice (LDS offset 0) ---
            {
                uint* hr = hb1 + ((t + 1) & 1) * 4096;
                i32x4 av[2][8];
#pragma unroll
                for (int mt = 0; mt < 2; ++mt)
#pragma unroll
                    for (int kk = 0; kk < 8; ++kk) {
                        int idx = (((kk * 4 + kg) * 32) + mt * 16 + cl) * 4;
                        i32x4 v;
#pragma unroll
                        for (int d = 0; d < 4; ++d) v[d] = (int)ld_rel(hr + idx + d);
                        av[mt][kk] = v;
                    }
#pragma unroll
                for (int gi = 0; gi < 3; ++gi)
#pragma unroll
                    for (int kk = 0; kk < 8; ++kk) {
                        f16x8 B = *(const f16x8*)&Wlds[(((((gi * 2 + w) * 8) + kk) * 4 + kg) * 16 + cl) * 8];
                        const int ai = (gi == 2) ? 3 : gi;
#pragma unroll
                        for (int mt = 0; mt < 2; ++mt)
                            acc[mt][ai] = __builtin_amdgcn_mfma_f32_16x16x32_f16(
                                __builtin_bit_cast(f16x8, av[mt][kk]), B, acc[mt][ai], 0, 0, 0);
                    }
            }

            // activations + publish h1(t) to slot t&1
            uint* hbw = hb1 + (t & 1) * 4096;
#pragma unroll
            for (int mt = 0; mt < 2; ++mt)
#pragma unroll
                for (int j = 0; j < 4; ++j) {
                    int j8 = mt * 4 + j;
                    int row = mt * 16 + kg * 4 + j;
                    float r  = fsigm(acc[mt][0][j]);
                    float z  = fsigm(acc[mt][1][j]);
                    float nn = ftanh(acc[mt][2][j] + r * acc[mt][3][j]);
                    float h  = nn + z * (hm[j8] - nn);
                    hm[j8] = h;
                    unsigned short hb16 = __builtin_bit_cast(unsigned short, (_Float16)h);
                    int other = __shfl_xor((int)hb16, 1);
                    if ((cl & 1) == 0) {
                        uint word = (uint)hb16 | ((uint)(unsigned short)other << 16);
                        st_rel(hbw + ((c >> 3) * 32 + row) * 4 + ((c & 7) >> 1), word);
                    }
                    if (t == TT - 1)
                        h1st[(size_t)(g * 32 + row) * HH + c] = h;
                }
        }
        __syncthreads();
        if (tid == 0) {
            __hip_atomic_fetch_add(c0, 1u, __ATOMIC_RELAXED, __HIP_MEMORY_SCOPE_AGENT);
            __hip_atomic_fetch_add(f1, 1u, __ATOMIC_RELEASE, __HIP_MEMORY_SCOPE_AGENT);
        }
    }
}

__global__ void __launch_bounds__(256)
rec_all(const _Float16* __restrict__ wl0, const _Float16* __restrict__ wl1h,
        const _Float16* __restrict__ wl1i,
        const float* __restrict__ x, const float* __restrict__ wih0,
        const float* __restrict__ bih0, const float* __restrict__ bhh0,
        const float* __restrict__ bih1, const float* __restrict__ bhh1,
        uint* hbuf0, uint* hbuf1, uint* flags, float* __restrict__ h1st)
{
    // bid -> (xcd, role): co-locates each group's 12 blocks on one XCD if
    // blockIdx%8 == XCD (speed-only assumption; correctness via agent atomics)
    const int bid = blockIdx.x;                      // 0..191
    const int xcd = bid & 7, slot = bid >> 3;        // slot 0..23
    const int g = xcd * 2 + (slot / 12);             // group 0..15
    const int s = slot % 12;                         // 0-3: L0, 4-11: L1
    __shared__ __align__(16) _Float16 Wlds[49152];   // 96KB
    if (s < 4)
        rec0_body(g, s, Wlds, wl0, x, bih0, bhh0, wih0, hbuf0, flags);
    else
        rec1_body(g, s - 4, Wlds, wl1h, wl1i, bih1, bhh1, hbuf0, hbuf1, flags, h1st);
}

// ---------------------------------------------------------------------------
// prep: weights -> per-block LDS-ready f16 fragment slices.
// unit r = ((nt*8+kk)*4+kg)*16+cl ; value = w[col][ (kk*4+kg)*8 .. +8 ]
// ---------------------------------------------------------------------------
__global__ void __launch_bounds__(256)
prep_kernel(const float* __restrict__ whh0, const float* __restrict__ whh1,
            const float* __restrict__ wih1,
            _Float16* __restrict__ wl0, _Float16* __restrict__ wl1h,
            _Float16* __restrict__ wl1i)
{
    const int u = blockIdx.x * 256 + threadIdx.x;    // 0..73727
    const float* src; _Float16* dst; int col, k0;
    if (u < 24576) {                                 // L0: 4 slices x 6144
        int m = u / 6144, r = u % 6144;
        int cl = r & 15, kg = (r >> 4) & 3, kk = (r >> 6) & 7, nt = r >> 9;  // nt 0..11
        col = (nt >> 2) * HH + m * 64 + (nt & 3) * 16 + cl;
        k0 = (kk * 4 + kg) * 8;
        src = whh0; dst = wl0 + (size_t)u * 8;
    } else if (u < 49152) {                          // L1 hh: 8 slices x 3072
        int v = u - 24576, m = v / 3072, r = v % 3072;
        int cl = r & 15, kg = (r >> 4) & 3, kk = (r >> 6) & 7, nt = r >> 9;  // nt 0..5
        col = (nt >> 1) * HH + m * 32 + (nt & 1) * 16 + cl;
        k0 = (kk * 4 + kg) * 8;
        src = whh1; dst = wl1h + (size_t)v * 8;
    } else {                                         // L1 ih: 8 slices x 3072
        int v = u - 49152, m = v / 3072, r = v % 3072;
        int cl = r & 15, kg = (r >> 4) & 3, kk = (r >> 6) & 7, nt = r >> 9;
        col = (nt >> 1) * HH + m * 32 + (nt & 1) * 16 + cl;
        k0 = (kk * 4 + kg) * 8;
        src = wih1; dst = wl1i + (size_t)v * 8;
    }
    f32x4 f0 = *(const f32x4*)(src + (size_t)col * HH + k0);
    f32x4 f1 = *(const f32x4*)(src + (size_t)col * HH + k0 + 4);
    f16x8 h;
    h[0] = (_Float16)f0[0]; h[1] = (_Float16)f0[1];
    h[2] = (_Float16)f0[2]; h[3] = (_Float16)f0[3];
    h[4] = (_Float16)f1[0]; h[5] = (_Float16)f1[1];
    h[6] = (_Float16)f1[2]; h[7] = (_Float16)f1[3];
    *(f16x8*)dst = h;
}

__global__ void __launch_bounds__(256)
init_kernel(uint* p, int n)
{
    int i = blockIdx.x * 256 + threadIdx.x;
    if (i < n) p[i] = 0;
}

// out[b] = h1[b,:] . w_fc + b_fc  (one wave per batch row)
__global__ void __launch_bounds__(64)
fc_kernel(const float* __restrict__ h, const float* __restrict__ wfc,
          const float* __restrict__ bfc, float* __restrict__ out)
{
    const int b = blockIdx.x, l = threadIdx.x;
    f32x4 hv = *(const f32x4*)(h + (size_t)b * HH + l * 4);
    f32x4 wv = *(const f32x4*)(wfc + l * 4);
    float s = hv[0] * wv[0] + hv[1] * wv[1] + hv[2] * wv[2] + hv[3] * wv[3];
#pragma unroll
    for (int off = 32; off; off >>= 1) s += __shfl_down(s, off);
    if (l == 0) out[b] = s + bfc[0];
}

extern "C" void kernel_launch(void* const* d_in, const int* in_sizes, int n_in,
                              void* d_out, int out_size, void* d_ws, size_t ws_size,
                              hipStream_t stream)
{
    (void)in_sizes; (void)n_in; (void)out_size;

    const float* x    = (const float*)d_in[0];
    const float* wih0 = (const float*)d_in[1];
    const float* whh0 = (const float*)d_in[2];
    const float* bih0 = (const float*)d_in[3];
    const float* bhh0 = (const float*)d_in[4];
    const float* wih1 = (const float*)d_in[5];
    const float* whh1 = (const float*)d_in[6];
    const float* bih1 = (const float*)d_in[7];
    const float* bhh1 = (const float*)d_in[8];
    const float* wfc  = (const float*)d_in[9];
    const float* bfc  = (const float*)d_in[10];
    float* out = (float*)d_out;

    char* p = (char*)d_ws;
    _Float16* wl0  = (_Float16*)p; p += (size_t)24576 * 8 * 2;   // 384KB
    _Float16* wl1h = (_Float16*)p; p += (size_t)24576 * 8 * 2;   // 384KB
    _Float16* wl1i = (_Float16*)p; p += (size_t)24576 * 8 * 2;   // 384KB
    uint* hbuf0 = (uint*)p; p += (size_t)NG * 4 * 4096 * 4;      // 1MB
    uint* hbuf1 = (uint*)p; p += (size_t)NG * 2 * 4096 * 4;      // 512KB
    uint* flags = (uint*)p; p += 4096;                           // 768 used
    float* h1st = (float*)p; p += (size_t)BB * HH * 4;           // 512KB
    if ((size_t)(p - (char*)d_ws) > ws_size) return;             // loud failure

    const int nzero = NG * 4 * 4096 + NG * 2 * 4096 + 1024;      // hbuf0+hbuf1+flags (contiguous)
    init_kernel<<<(nzero + 255) / 256, 256, 0, stream>>>(hbuf0, nzero);
    prep_kernel<<<288, 256, 0, stream>>>(whh0, whh1, wih1, wl0, wl1h, wl1i);
    rec_all<<<192, 256, 0, stream>>>(wl0, wl1h, wl1i, x, wih0,
                                     bih0, bhh0, bih1, bhh1,
                                     hbuf0, hbuf1, flags, h1st);
    fc_kernel<<<BB, 64, 0, stream>>>(h1st, wfc, bfc, out);
}